// Round 4
// baseline (6070789.062 us; speedup 1.0000x reference)
//
#include <hip/hip_runtime.h>

// ---------- problem constants ----------
// V=50000, E=300, H=512, BS=64, NSEG=3, SLEN=256 -> B3=192
// NNODE=18, NFEAT=600, NHID=600, NOUT=1024

typedef unsigned short ushort_t;
typedef __attribute__((ext_vector_type(8))) short bf16x8;   // 8 bf16 = 4 VGPRs
typedef __attribute__((ext_vector_type(4))) float f32x4;
typedef __attribute__((ext_vector_type(4))) unsigned int u32x4;

// output element offsets (fp32 elements)
#define OUT_RFTS 0UL
#define OUT_EMBS 25165824UL          // 64*768*512
#define OUT_MSKS 39911424UL          // + 64*768*300
#define OUT_SG   39960576UL          // + 64*768
#define OUT_HIDS 41140224UL          // + 64*18*1024

// workspace byte offsets
#define WS_HX   0UL                  // hx: 2*192*512 bf16 = 393,216 B
#define WS_FLG  393216UL             // flags: 96 x 128B lines = 12,288 B
// probe scratch: ws + 405504 (NOT memset -> poison 0xAA detects cross-XCD)

__device__ __forceinline__ ushort_t f2b(float f) {
  unsigned int u = __float_as_uint(f);
  u += 0x7fffu + ((u >> 16) & 1u);          // RNE
  return (ushort_t)(u >> 16);
}

union FRAG { ushort_t s[8]; bf16x8 v; uint2 u2[2]; };

__device__ __forceinline__ bf16x8 frag_from_f32(const float* p, bool v0, bool v1) {
  float4 a = v0 ? *(const float4*)p       : make_float4(0.f, 0.f, 0.f, 0.f);
  float4 b = v1 ? *(const float4*)(p + 4) : make_float4(0.f, 0.f, 0.f, 0.f);
  FRAG u;
  u.s[0] = f2b(a.x); u.s[1] = f2b(a.y); u.s[2] = f2b(a.z); u.s[3] = f2b(a.w);
  u.s[4] = f2b(b.x); u.s[5] = f2b(b.y); u.s[6] = f2b(b.z); u.s[7] = f2b(b.w);
  return u.v;
}

// ---- scope-explicit exchange helpers ----
// fast (same-XCD) : sc0      -> bypass L1, coherent at the XCD's shared L2
// slow (any)      : sc0 sc1  -> bypass L1+L2, coherent at MALL (r1/r3-proven)
__device__ __forceinline__ unsigned int ld_scope(bool fast, const unsigned int* a) {
  unsigned int v;
  if (fast) asm volatile("global_load_dword %0, %1, off sc0\n\t"
                         "s_waitcnt vmcnt(0)" : "=v"(v) : "v"(a) : "memory");
  else      asm volatile("global_load_dword %0, %1, off sc0 sc1\n\t"
                         "s_waitcnt vmcnt(0)" : "=v"(v) : "v"(a) : "memory");
  return v;
}
__device__ __forceinline__ void st_scope(bool fast, void* a, unsigned int v) {
  if (fast) asm volatile("global_store_dword %0, %1, off sc0"
                         :: "v"(a), "v"(v) : "memory");
  else      asm volatile("global_store_dword %0, %1, off sc0 sc1"
                         :: "v"(a), "v"(v) : "memory");
}
__device__ __forceinline__ void ld4x16_scope(bool fast,
    const char* a0, const char* a1, const char* a2, const char* a3,
    u32x4& v0, u32x4& v1, u32x4& v2, u32x4& v3) {
  if (fast) asm volatile(
      "global_load_dwordx4 %0, %4, off sc0\n\t"
      "global_load_dwordx4 %1, %5, off sc0\n\t"
      "global_load_dwordx4 %2, %6, off sc0\n\t"
      "global_load_dwordx4 %3, %7, off sc0\n\t"
      "s_waitcnt vmcnt(0)"
      : "=&v"(v0), "=&v"(v1), "=&v"(v2), "=&v"(v3)
      : "v"(a0), "v"(a1), "v"(a2), "v"(a3) : "memory");
  else asm volatile(
      "global_load_dwordx4 %0, %4, off sc0 sc1\n\t"
      "global_load_dwordx4 %1, %5, off sc0 sc1\n\t"
      "global_load_dwordx4 %2, %6, off sc0 sc1\n\t"
      "global_load_dwordx4 %3, %7, off sc0 sc1\n\t"
      "s_waitcnt vmcnt(0)"
      : "=&v"(v0), "=&v"(v1), "=&v"(v2), "=&v"(v3)
      : "v"(a0), "v"(a1), "v"(a2), "v"(a3) : "memory");
}

// =====================================================================
// ONE dispatch, 256 blocks, 1 block/CU. XCD-copacked role map assuming
// round-robin bid%8 -> XCD (m09): each GRU group's 8 slices share an XCD.
//   XCD 0..3 : groups {x, x+8} (16 WGs) + 16 GCN blocks
//   XCD 4..7 : group x (8 WGs) + 24 pack blocks
// Runtime gate: XCC_ID exchange + end-to-end sc0 probe, decided by slice 0,
// all through the r1/r3-proven MALL protocol. Fallback = exact r3 protocol.
// Flag lines are ONLY ever touched by scope-explicit asm ops.
// Flag line dwords: [0]=step, [16]=xcc, [17]=probe-ready(p0), [18]=verdict,
//                   [19]=decision(p0).
// =====================================================================
__global__ __launch_bounds__(256, 1) void fused_all(
    const int* __restrict__ inds, const int* __restrict__ lens,
    const float* __restrict__ emb, const float* __restrict__ w_ih,
    const float* __restrict__ w_hh, const float* __restrict__ b_ih,
    const float* __restrict__ b_hh,
    const float* __restrict__ sgx, const float* __restrict__ adj,
    const float* __restrict__ gw1, const float* __restrict__ gb1,
    const float* __restrict__ gw2, const float* __restrict__ gb2,
    ushort_t* __restrict__ hx, unsigned int* __restrict__ flags,
    float* __restrict__ out)
{
  __shared__ __attribute__((aligned(16))) char smem[92304];
  const int bid = blockIdx.x;
  const int tid = threadIdx.x;
  const int x = bid & 7;          // presumed XCD (m09 round-robin)
  const int s = bid >> 3;         // slot on that XCD (0..31)

  int role, g = 0, p = 0, gcnb = 0, packid = 0;
  if (x < 4) {
    if (s < 8)       { role = 0; g = x;     p = s; }
    else if (s < 16) { role = 0; g = x + 8; p = s - 8; }
    else             { role = 1; gcnb = x * 16 + (s - 16); }   // 0..63
  } else {
    if (s < 8)       { role = 0; g = x;     p = s; }
    else             { role = 2; packid = (x - 4) * 24 + (s - 8); } // 0..95
  }

  if (role == 0) {
    // ================= GRU =================
    ushort_t* hst = (ushort_t*)smem;                                   // 16*520
    ushort_t* tokb = (ushort_t*)(smem + 16640);                        // [2][16*328]
    int* sidx = (int*)(smem + 37632);                                  // 16 ints
    int* s_dec = (int*)(smem + 37696);

    const int w = tid >> 6;
    const int l = tid & 63;
    const int jc = l & 15;
    const int quad = l >> 4;
    const int jg = p * 64 + w * 16 + jc;
    const int fl = (g * 8 + p) * 32;       // own flag line (dword index)

    // probe dword for this group (ws+405504 region; NOT memset -> 0xAA poison)
    unsigned int* prb = (unsigned int*)((char*)flags + 12288) + g * 32;
    const unsigned int MAGIC = 0xAB5C0000u | (unsigned)g;

    // ---- phase A: publish own XCC_ID via MALL (early; gathered later) ----
    const unsigned int xcc =
        ((unsigned)__builtin_amdgcn_s_getreg((31 << 11) | (0 << 6) | 20)) & 0xffu;
    if (tid == 0)
      st_scope(false, (void*)&flags[fl + 16], 0x1000u | xcc);

    // ---- register/AGPR-resident w_hh slice ----
    bf16x8 bwh[3][16];
#pragma unroll
    for (int g3 = 0; g3 < 3; ++g3) {
      const float* wr = w_hh + (size_t)(g3 * 512 + jg) * 512 + quad * 8;
#pragma unroll
      for (int kc = 0; kc < 16; ++kc)
        bwh[g3][kc] = frag_from_f32(wr + kc * 32, true, true);
    }
    // ---- register-resident w_ih slice (K=300 padded to 320) ----
    bf16x8 bwx[3][10];
#pragma unroll
    for (int g3 = 0; g3 < 3; ++g3) {
      const float* wr = w_ih + (size_t)(g3 * 512 + jg) * 300;
#pragma unroll
      for (int kc = 0; kc < 10; ++kc) {
        const int k0 = kc * 32 + quad * 8;
        bwx[g3][kc] = frag_from_f32(wr + k0, k0 + 3 < 300, k0 + 7 < 300);
      }
    }
    const float bsr = b_ih[jg] + b_hh[jg];
    const float bsz = b_ih[512 + jg] + b_hh[512 + jg];
    const float bin = b_ih[1024 + jg];
    const float bhn = b_hh[1024 + jg];

    int Tg = 0;
    for (int i = 0; i < 16; ++i) Tg = max(Tg, lens[g * 16 + i]);

    int len_q[4]; size_t rf_q[4], hxo_q[4], hid_q[4];
    float h_q[4] = {0.f, 0.f, 0.f, 0.f};
#pragma unroll
    for (int q = 0; q < 4; ++q) {
      int sl = quad * 4 + q;
      int b3 = g * 16 + sl;
      len_q[q] = lens[b3];
      int b = b3 / 3, seg = b3 - b * 3;
      int off = 0;
      for (int ss = 0; ss < seg; ++ss) off += lens[b * 3 + ss];
      rf_q[q]  = OUT_RFTS + ((size_t)b * 768 + off) * 512 + jg;
      hxo_q[q] = (size_t)b3 * 512 + (size_t)(jg & ~1);
      hid_q[q] = OUT_HIDS + (size_t)b3 * 512 + jg;
    }

    int trow[5], tcu[5];
#pragma unroll
    for (int c = 0; c < 5; ++c) {
      int u = c * 256 + tid;
      trow[c] = u / 80;
      tcu[c]  = u - trow[c] * 80;
    }

    // ---- prologue: stage tok(t=0) ----
    if (tid < 16) sidx[tid] = inds[(size_t)(g * 16 + tid) * 256 + 0];
    __syncthreads();
#pragma unroll
    for (int c = 0; c < 5; ++c) {
      float4 v = make_float4(0.f, 0.f, 0.f, 0.f);
      if (tcu[c] < 75)
        v = *(const float4*)(emb + (size_t)sidx[trow[c]] * 300 + tcu[c] * 4);
      FRAG u; u.s[0] = f2b(v.x); u.s[1] = f2b(v.y); u.s[2] = f2b(v.z); u.s[3] = f2b(v.w);
      *(uint2*)(&tokb[trow[c] * 328 + tcu[c] * 4]) = u.u2[0];
    }

    // ---- phases B-E: XCC gather, probe, verdict, decision (tid0 only) ----
    if (tid == 0) {
      int ok = 1;
      for (int i = 0; i < 8; ++i) {
        const unsigned int* fa = &flags[(g * 8 + i) * 32 + 16];
        unsigned int v; long gd = 0;
        for (;;) { v = ld_scope(false, fa);
                   if (v != 0u || gd > 2000000L) break;
                   ++gd; __builtin_amdgcn_s_sleep(1); }
        if (v != (0x1000u | xcc)) ok = 0;
      }
      if (p == 0 && ok) {
        st_scope(true, (void*)prb, MAGIC);                   // the actual fast path
        asm volatile("s_waitcnt vmcnt(0)" ::: "memory");
      }
      if (p == 0)
        st_scope(false, (void*)&flags[fl + 17], ok ? 1u : 2u);
      {
        const unsigned int* fa = &flags[(g * 8 + 0) * 32 + 17];
        unsigned int v; long gd = 0;
        for (;;) { v = ld_scope(false, fa);
                   if (v != 0u || gd > 2000000L) break;
                   ++gd; __builtin_amdgcn_s_sleep(1); }
        if (v == 1u) {
          unsigned int pv = ld_scope(true, prb);             // end-to-end check
          if (pv != MAGIC) ok = 0;
        } else ok = 0;
      }
      st_scope(false, (void*)&flags[fl + 18], ok ? 2u : 3u);
      if (p == 0) {
        int allok = 1;
        for (int i = 0; i < 8; ++i) {
          const unsigned int* fa = &flags[(g * 8 + i) * 32 + 18];
          unsigned int v; long gd = 0;
          for (;;) { v = ld_scope(false, fa);
                     if (v != 0u || gd > 2000000L) break;
                     ++gd; __builtin_amdgcn_s_sleep(1); }
          if (v != 2u) allok = 0;
        }
        st_scope(false, (void*)&flags[fl + 19], allok ? 2u : 3u);
      }
      {
        const unsigned int* fa = &flags[(g * 8 + 0) * 32 + 19];
        unsigned int v; long gd = 0;
        for (;;) { v = ld_scope(false, fa);
                   if (v != 0u || gd > 3000000L) break;
                   ++gd; __builtin_amdgcn_s_sleep(1); }
        *s_dec = (v == 2u) ? 1 : 0;
      }
    }
    __syncthreads();
    const bool fast = (*s_dec != 0);

    const int HXE = 192 * 512;
    const f32x4 z4 = {0.f, 0.f, 0.f, 0.f};

    for (int t = 0; t < Tg; ++t) {
      const int buf = t & 1, nbuf = buf ^ 1;
      // ---- x-part MFMAs FIRST (h-independent; hides publish->detect) ----
      f32x4 accr = z4, accz = z4, anh = z4, anx = z4;
      const ushort_t* tokc = tokb + buf * (16 * 328);
#pragma unroll
      for (int kc = 0; kc < 10; ++kc) {
        bf16x8 xf = *(const bf16x8*)(&tokc[(l & 15) * 328 + kc * 32 + quad * 8]);
        accr = __builtin_amdgcn_mfma_f32_16x16x32_bf16(xf, bwx[0][kc], accr, 0, 0, 0);
        accz = __builtin_amdgcn_mfma_f32_16x16x32_bf16(xf, bwx[1][kc], accz, 0, 0, 0);
        anx  = __builtin_amdgcn_mfma_f32_16x16x32_bf16(xf, bwx[2][kc], anx, 0, 0, 0);
      }
      // ---- per-wave poll for all 8 peer flags >= t ----
      if (l < 8) {
        const unsigned int* fa = &flags[(g * 8 + l) * 32];
        long gd = 0;
        if (fast) {
          while (ld_scope(true, fa) < (unsigned int)t)
            if (++gd > 300000L) break;          // hot spin: L2 RT is cheap
        } else {
          while (ld_scope(false, fa) < (unsigned int)t) {
            __builtin_amdgcn_s_sleep(1);
            if (++gd > 100000L) break;
          }
        }
      }
      if (tid < 16) {
        int tt = (t + 1 < 256) ? t + 1 : 255;
        sidx[tid] = inds[(size_t)(g * 16 + tid) * 256 + tt];
      }
      // ---- stage h (scope loads; ordered after this wave's own poll) ----
      {
        const char* hsrc = (const char*)(hx + (size_t)buf * HXE + (size_t)g * 16 * 512);
        u32x4 v0, v1, v2, v3;
        ld4x16_scope(fast,
                     hsrc + (size_t)(0 * 256 + tid) * 16,
                     hsrc + (size_t)(1 * 256 + tid) * 16,
                     hsrc + (size_t)(2 * 256 + tid) * 16,
                     hsrc + (size_t)(3 * 256 + tid) * 16,
                     v0, v1, v2, v3);
        const int i0 = tid, i1 = 256 + tid, i2 = 512 + tid, i3 = 768 + tid;
        *(u32x4*)(&hst[(i0 >> 6) * 520 + (i0 & 63) * 8]) = v0;
        *(u32x4*)(&hst[(i1 >> 6) * 520 + (i1 & 63) * 8]) = v1;
        *(u32x4*)(&hst[(i2 >> 6) * 520 + (i2 & 63) * 8]) = v2;
        *(u32x4*)(&hst[(i3 >> 6) * 520 + (i3 & 63) * 8]) = v3;
      }
      __syncthreads();                 // B1: hst + sidx ready for all waves
      // ---- tok prefetch for t+1 (plain loads; in flight during h-MFMAs) ----
      float4 tr[5];
#pragma unroll
      for (int c = 0; c < 5; ++c) {
        tr[c] = make_float4(0.f, 0.f, 0.f, 0.f);
        if (tcu[c] < 75)
          tr[c] = *(const float4*)(emb + (size_t)sidx[trow[c]] * 300 + tcu[c] * 4);
      }
      // ---- h-part MFMAs ----
#pragma unroll
      for (int kc = 0; kc < 16; ++kc) {
        bf16x8 af = *(const bf16x8*)(&hst[(l & 15) * 520 + kc * 32 + quad * 8]);
        accr = __builtin_amdgcn_mfma_f32_16x16x32_bf16(af, bwh[0][kc], accr, 0, 0, 0);
        accz = __builtin_amdgcn_mfma_f32_16x16x32_bf16(af, bwh[1][kc], accz, 0, 0, 0);
        anh  = __builtin_amdgcn_mfma_f32_16x16x32_bf16(af, bwh[2][kc], anh, 0, 0, 0);
      }
      // ---- gate math + h publish (critical path first) ----
      ushort_t* hxout = hx + (size_t)nbuf * HXE;
#pragma unroll
      for (int q = 0; q < 4; ++q) {
        float pr = accr[q] + bsr;
        float pz = accz[q] + bsz;
        float r = 1.f / (1.f + __expf(-pr));
        float z = 1.f / (1.f + __expf(-pz));
        float e2 = __expf(2.f * (anx[q] + bin + r * (anh[q] + bhn)));
        float n = 1.f - 2.f / (e2 + 1.f);          // tanh
        float hn = (1.f - z) * n + z * h_q[q];
        hn = (t < len_q[q]) ? hn : h_q[q];
        h_q[q] = hn;
        unsigned int hb = f2b(hn);
        unsigned int ob = (unsigned int)__shfl_xor((int)hb, 1, 64) & 0xffffu;
        if ((jc & 1) == 0) {
          unsigned int pv = (hb & 0xffffu) | (ob << 16);
          st_scope(fast, (void*)(hxout + hxo_q[q]), pv);
        }
      }
      asm volatile("s_waitcnt vmcnt(0)" ::: "memory");  // h stores acked (all waves)
      // ---- tok commit for t+1 (tr drained by the vmcnt above) ----
#pragma unroll
      for (int c = 0; c < 5; ++c) {
        FRAG u;
        u.s[0] = f2b(tr[c].x); u.s[1] = f2b(tr[c].y);
        u.s[2] = f2b(tr[c].z); u.s[3] = f2b(tr[c].w);
        *(uint2*)(&tokb[nbuf * (16 * 328) + trow[c] * 328 + tcu[c] * 4]) = u.u2[0];
      }
      __syncthreads();                 // B2: all waves' h stores acked + tok ready
      if (tid == 0)
        st_scope(fast, (void*)&flags[fl], (unsigned int)(t + 1));
      // off the critical chain: rfts fp32 stores
#pragma unroll
      for (int q = 0; q < 4; ++q)
        if (t < len_q[q]) out[rf_q[q] + (size_t)t * 512] = h_q[q];
    }
#pragma unroll
    for (int q = 0; q < 4; ++q) out[hid_q[q]] = h_q[q];

  } else if (role == 1) {
    // ================= GCN: one block per sample ================
    const int b = gcnb;
    float* xs   = (float*)smem;            // 18*600
    float* h1s  = (float*)smem + 10800;    // 18*600
    float* adjs = (float*)smem + 21600;    // 324
    float* ts   = (float*)smem + 21924;    // 1152

    for (int i = tid; i < 18 * 600; i += 256) xs[i] = sgx[(size_t)b * 10800 + i];
    for (int i = tid; i < 324; i += 256) adjs[i] = adj[(size_t)b * 324 + i];
    __syncthreads();

    for (int cb = 0; cb < 10; ++cb) {
      const int c0 = cb * 64;
      for (int o = tid; o < 1152; o += 256) {
        const int r = o >> 6, c = c0 + (o & 63);
        float a0 = 0.f, a1 = 0.f;
        if (c < 600) {
          const float* xr = xs + r * 600;
          for (int k = 0; k < 600; k += 2) {
            a0 += xr[k]     * gw1[(size_t)k * 600 + c];
            a1 += xr[k + 1] * gw1[(size_t)(k + 1) * 600 + c];
          }
        }
        ts[o] = a0 + a1;
      }
      __syncthreads();
      for (int o = tid; o < 1152; o += 256) {
        const int n = o >> 6, cl = o & 63, c = c0 + cl;
        if (c < 600) {
          float acc = gb1[c];
#pragma unroll
          for (int m = 0; m < 18; ++m) acc += adjs[n * 18 + m] * ts[m * 64 + cl];
          h1s[n * 600 + c] = fmaxf(acc, 0.f);
        }
      }
      __syncthreads();
    }
    for (int cb = 0; cb < 16; ++cb) {
      const int c0 = cb * 64;
      for (int o = tid; o < 1152; o += 256) {
        const int r = o >> 6, c = c0 + (o & 63);
        const float* xr = h1s + r * 600;
        float a0 = 0.f, a1 = 0.f;
        for (int k = 0; k < 600; k += 2) {
          a0 += xr[k]     * gw2[(size_t)k * 1024 + c];
          a1 += xr[k + 1] * gw2[(size_t)(k + 1) * 1024 + c];
        }
        ts[o] = a0 + a1;
      }
      __syncthreads();
      for (int o = tid; o < 1152; o += 256) {
        const int n = o >> 6, cl = o & 63, c = c0 + cl;
        float acc = gb2[c];
#pragma unroll
        for (int m = 0; m < 18; ++m) acc += adjs[n * 18 + m] * ts[m * 64 + cl];
        out[OUT_SG + (size_t)b * 18432 + n * 1024 + c] = acc;
      }
      __syncthreads();
    }

  } else {
    // ================= pack: out_embs + out_msks + rfts tail zeros =========
    // 96 blocks x 4 waves = 384 waves; 64*768 = 49152 (b,p) pairs, 128/wave.
    const int wid = packid * 4 + (tid >> 6);     // 0..383
    const int l = tid & 63;
    for (int j = 0; j < 128; ++j) {
      const int pr = wid + 384 * j;              // 0..49151
      const int b = pr / 768;
      const int pp = pr - b * 768;
      const int l0 = lens[b * 3], l1 = lens[b * 3 + 1], l2v = lens[b * 3 + 2];
      const int tlen = l0 + l1 + l2v;
      if (l == 0)
        out[OUT_MSKS + (size_t)b * 768 + pp] = (pp < tlen) ? 1.0f : 0.0f;
      const size_t rfoff = OUT_RFTS + ((size_t)b * 768 + pp) * 512;
      const size_t eboff = OUT_EMBS + ((size_t)b * 768 + pp) * 300;
      if (pp >= tlen) {
        const float4 zz = make_float4(0.f, 0.f, 0.f, 0.f);
        *(float4*)(out + rfoff + (size_t)l * 8)     = zz;
        *(float4*)(out + rfoff + (size_t)l * 8 + 4) = zz;
        for (int u = l; u < 75; u += 64)
          *(float4*)(out + eboff + (size_t)u * 4) = zz;
      } else {
        int sgi, tt;
        if (pp < l0)           { sgi = 0; tt = pp; }
        else if (pp < l0 + l1) { sgi = 1; tt = pp - l0; }
        else                   { sgi = 2; tt = pp - l0 - l1; }
        const int ind = inds[(b * 3 + sgi) * 256 + tt];
        const float* src = emb + (size_t)ind * 300;
        for (int u = l; u < 75; u += 64)
          *(float4*)(out + eboff + (size_t)u * 4) = *(const float4*)(src + (size_t)u * 4);
      }
    }
  }
}

// =====================================================================
extern "C" void kernel_launch(void* const* d_in, const int* in_sizes, int n_in,
                              void* d_out, int out_size, void* d_ws, size_t ws_size,
                              hipStream_t stream)
{
  (void)in_sizes; (void)n_in; (void)out_size; (void)ws_size;
  const int*   inds = (const int*)d_in[0];
  const int*   lens = (const int*)d_in[1];
  const float* emb  = (const float*)d_in[2];
  const float* w_ih = (const float*)d_in[3];
  const float* w_hh = (const float*)d_in[4];
  const float* b_ih = (const float*)d_in[5];
  const float* b_hh = (const float*)d_in[6];
  const float* sgx  = (const float*)d_in[7];
  const float* adj  = (const float*)d_in[8];
  const float* gw1  = (const float*)d_in[9];
  const float* gb1  = (const float*)d_in[10];
  const float* gw2  = (const float*)d_in[11];
  const float* gb2  = (const float*)d_in[12];
  float* out = (float*)d_out;
  char* ws = (char*)d_ws;
  ushort_t* hx = (ushort_t*)(ws + WS_HX);
  unsigned int* flags = (unsigned int*)(ws + WS_FLG);

  // zero h0 double-buffer + flags; probe scratch (ws+405504) stays poisoned
  // on purpose (cross-XCD probe must read stale non-magic data).
  hipMemsetAsync(ws, 0, 405504, stream);
  fused_all<<<dim3(256), 256, 0, stream>>>(inds, lens, emb, w_ih, w_hh, b_ih, b_hh,
                                           sgx, adj, gw1, gb1, gw2, gb2,
                                           hx, flags, out);
}